// Round 12
// baseline (185.355 us; speedup 1.0000x reference)
//
#include <hip/hip_runtime.h>
#include <hip/hip_bf16.h>

#define NTOK 8192
#define NCH  256
#define TT   128         // tokens per tile
#define XTP  264         // stride (u16) for [tok][ch] LDS tiles (16B-aligned rows)
#define EK2  136         // stride (u16) for [ch][tok] LDS tiles (16B-aligned rows)
#define NBLK 256         // persistent grid: 1 block/CU (forced by 139 KB LDS)

typedef unsigned short u16;
typedef __attribute__((ext_vector_type(8))) short bf16x8;   // MFMA A/B frag (4 VGPR)
typedef __attribute__((ext_vector_type(4))) float f32x4;    // MFMA C/D frag
typedef __attribute__((ext_vector_type(8))) unsigned short u16x8;
typedef __attribute__((ext_vector_type(4))) unsigned short u16x4;

// Hardware bf16 conversions (RNE, v_cvt path) — r10-verified
__device__ __forceinline__ float b2f(u16 v){
  union { u16 u; __hip_bfloat16 h; } c; c.u = v; return __bfloat162float(c.h);
}
__device__ __forceinline__ u16 f2b(float f){
  union { __hip_bfloat16 h; u16 u; } c; c.h = __float2bfloat16(f); return c.u;
}
__device__ __forceinline__ f32x4 mfma16(bf16x8 a, bf16x8 b, f32x4 c){
  return __builtin_amdgcn_mfma_f32_16x16x32_bf16(a, b, c, 0, 0, 0);
}

// Hand-rolled grid barrier — functionally verified in this harness (round 4
// passed correctness with it). All NBLK blocks co-resident by construction:
// 139 KB LDS -> exactly 1 block/CU, grid == 256 == CU count.
__device__ __forceinline__ void grid_sync(unsigned* cnt, int t) {
  __syncthreads();
  if (t == 0) {
    __threadfence();
    __hip_atomic_fetch_add(cnt, 1u, __ATOMIC_ACQ_REL, __HIP_MEMORY_SCOPE_AGENT);
    while (__hip_atomic_load(cnt, __ATOMIC_ACQUIRE, __HIP_MEMORY_SCOPE_AGENT) < NBLK)
      __builtin_amdgcn_s_sleep(1);
    __threadfence();
  }
  __syncthreads();
}

// ---------------------------------------------------------------------------
// stage_xtile: global fp32 x tile [256 ch][128 tok] -> bf16 LDS dst [tok][XTP]
// via scratch [ch][EK2]. 512 threads. One internal barrier; caller MUST
// __syncthreads() after return before reading dst or overwriting scratch.
// (r11-verified TT=128 stage)
// ---------------------------------------------------------------------------
__device__ __forceinline__ void stage_xtile(const float* __restrict__ xb,
                                            u16* scratch, u16* dst, int t)
{
  #pragma unroll
  for (int i = 0; i < 8; ++i) {
    int ch = i * 32 + (t >> 4);          // 32 ch rows per iteration
    int tk = (t & 15) * 8;               // 8 consecutive tokens
    const float* p = xb + (size_t)ch * NTOK + tk;
    float4 v0 = *(const float4*)p;
    float4 v1 = *(const float4*)(p + 4);
    u16x8 pk;
    pk[0]=f2b(v0.x); pk[1]=f2b(v0.y); pk[2]=f2b(v0.z); pk[3]=f2b(v0.w);
    pk[4]=f2b(v1.x); pk[5]=f2b(v1.y); pk[6]=f2b(v1.z); pk[7]=f2b(v1.w);
    *(u16x8*)&scratch[ch * EK2 + tk] = pk;
  }
  __syncthreads();
  // transpose: scratch[ch][tok] -> dst[tok][ch]
  #pragma unroll
  for (int p2 = 0; p2 < 8; ++p2) {
    int idx = p2 * 512 + t;              // 0..4095
    int tok = idx & 127;
    int ch = (idx >> 7) * 8;
    u16x8 o;
    #pragma unroll
    for (int j = 0; j < 8; ++j) o[j] = scratch[(ch + j) * EK2 + tok];
    *(u16x8*)&dst[tok * XTP + ch] = o;
  }
}

// ---------------------------------------------------------------------------
// k_prep: convert Wk/Wq/Wv/Wr fp32 -> bf16 into wbf (64 blocks); block 0
// zeroes the grid-sync counters (ws is poisoned every iteration).
// ---------------------------------------------------------------------------
__global__ __launch_bounds__(256)
void k_prep(const float* __restrict__ Wk, const float* __restrict__ Wq,
            const float* __restrict__ Wv, const float* __restrict__ Wr,
            u16* __restrict__ wbf, unsigned* __restrict__ cnt)
{
  const int t = threadIdx.x, bid = blockIdx.x;
  if (bid == 0 && t == 0) { cnt[0] = 0u; cnt[1] = 0u; }
  const int mat = bid >> 4;
  const float* src = (mat == 0) ? Wk : (mat == 1) ? Wq : (mat == 2) ? Wv : Wr;
  u16* dst = wbf + mat * 65536;
  const int base = (bid & 15) * 4096 + t * 16;
  #pragma unroll
  for (int i = 0; i < 4; ++i) {
    float4 v = *(const float4*)(src + base + i * 4);
    u16x4 pk; pk[0]=f2b(v.x); pk[1]=f2b(v.y); pk[2]=f2b(v.z); pk[3]=f2b(v.w);
    *(u16x4*)(dst + base + i * 4) = pk;
  }
}

// ---------------------------------------------------------------------------
// k_main (persistent, 256 blocks x 512 threads, 1 block/CU, 139 KB LDS):
//  Phase A = r11 k_ctx body (stage x; K-GEMM->exp->ekb; V-GEMM->vt;
//            ctx GEMM + denom row-sums -> streaming partial stores).
//  grid_sync
//  Phase B = r11 k_red spread over all 256 blocks (reduce 64 partials ->
//            ctxT bf16 + rdenomF).
//  grid_sync
//  Phase C = r11 k_out body (re-stage x, L3-warm; Q-GEMM->softmax->qn;
//            att GEMM; Wr GEMM; +bias +residual; store).
//  NO register state carried across syncs (r4's spill lesson).
// ---------------------------------------------------------------------------
__global__ __launch_bounds__(512, 2)
void k_main(const float* __restrict__ x, const u16* __restrict__ wbf,
            const float* __restrict__ bk, const float* __restrict__ bv,
            const float* __restrict__ bq, const float* __restrict__ br,
            u16* __restrict__ ctxPart, float* __restrict__ denomPart,
            u16* __restrict__ ctxT, float* __restrict__ rdenomF,
            float* __restrict__ out, unsigned* __restrict__ cnt)
{
  __shared__ u16 bufA[NCH * EK2];   // A: x tile [128][XTP] then vt; C: xs
  __shared__ u16 ekb[NCH * EK2];    // A: scratch then exp(K); C: scratch then qn/att

  const int t = threadIdx.x;
  const int b = blockIdx.x >> 6, g = blockIdx.x & 63;
  const int w = t >> 6, lane = t & 63;
  const int l15 = lane & 15, quad = lane >> 4;
  const u16* Wkb = wbf;
  const u16* Wqb = wbf + 65536;
  const u16* Wvb = wbf + 2 * 65536;
  const u16* Wrb = wbf + 3 * 65536;
  const float* xb = x + (size_t)b * NCH * NTOK + g * TT;

  // ======================= Phase A: ctx partials ==========================
  stage_xtile(xb, ekb, bufA, t);
  __syncthreads();   // bufA = x tile ready; ekb scratch reads done

  {
    f32x4 acc[2][8];

    // ---- K GEMM: D[och][tok], wave w owns och [32w, 32w+32) ----
    #pragma unroll
    for (int mi = 0; mi < 2; ++mi)
      #pragma unroll
      for (int nj = 0; nj < 8; ++nj) acc[mi][nj] = (f32x4)0.f;
    for (int k0 = 0; k0 < NCH; k0 += 32) {
      bf16x8 af[2], bx[8];
      #pragma unroll
      for (int mi = 0; mi < 2; ++mi)
        af[mi] = *(const bf16x8*)(Wkb + (size_t)(w * 32 + mi * 16 + l15) * NCH + k0 + quad * 8);
      #pragma unroll
      for (int nj = 0; nj < 8; ++nj)
        bx[nj] = *(const bf16x8*)&bufA[(nj * 16 + l15) * XTP + k0 + quad * 8];
      #pragma unroll
      for (int mi = 0; mi < 2; ++mi)
        #pragma unroll
        for (int nj = 0; nj < 8; ++nj) acc[mi][nj] = mfma16(af[mi], bx[nj], acc[mi][nj]);
    }
    // epilogue: bias + exp -> ekb [ch][tok] (wave-exclusive rows)
    #pragma unroll
    for (int mi = 0; mi < 2; ++mi) {
      float4 bb = *(const float4*)(bk + w * 32 + mi * 16 + quad * 4);
      #pragma unroll
      for (int nj = 0; nj < 8; ++nj) {
        int tok = nj * 16 + l15, chb = w * 32 + mi * 16 + quad * 4;
        ekb[(chb + 0) * EK2 + tok] = f2b(__expf(acc[mi][nj][0] + bb.x));
        ekb[(chb + 1) * EK2 + tok] = f2b(__expf(acc[mi][nj][1] + bb.y));
        ekb[(chb + 2) * EK2 + tok] = f2b(__expf(acc[mi][nj][2] + bb.z));
        ekb[(chb + 3) * EK2 + tok] = f2b(__expf(acc[mi][nj][3] + bb.w));
      }
    }

    // ---- V GEMM (re-uses acc regs) ----
    #pragma unroll
    for (int mi = 0; mi < 2; ++mi)
      #pragma unroll
      for (int nj = 0; nj < 8; ++nj) acc[mi][nj] = (f32x4)0.f;
    for (int k0 = 0; k0 < NCH; k0 += 32) {
      bf16x8 af[2], bx[8];
      #pragma unroll
      for (int mi = 0; mi < 2; ++mi)
        af[mi] = *(const bf16x8*)(Wvb + (size_t)(w * 32 + mi * 16 + l15) * NCH + k0 + quad * 8);
      #pragma unroll
      for (int nj = 0; nj < 8; ++nj)
        bx[nj] = *(const bf16x8*)&bufA[(nj * 16 + l15) * XTP + k0 + quad * 8];
      #pragma unroll
      for (int mi = 0; mi < 2; ++mi)
        #pragma unroll
        for (int nj = 0; nj < 8; ++nj) acc[mi][nj] = mfma16(af[mi], bx[nj], acc[mi][nj]);
    }
    __syncthreads();   // all waves done reading x tile; safe to overwrite with vt
    #pragma unroll
    for (int mi = 0; mi < 2; ++mi) {
      float4 bb = *(const float4*)(bv + w * 32 + mi * 16 + quad * 4);
      #pragma unroll
      for (int nj = 0; nj < 8; ++nj) {
        int tok = nj * 16 + l15, chb = w * 32 + mi * 16 + quad * 4;
        bufA[(chb + 0) * EK2 + tok] = f2b(acc[mi][nj][0] + bb.x);
        bufA[(chb + 1) * EK2 + tok] = f2b(acc[mi][nj][1] + bb.y);
        bufA[(chb + 2) * EK2 + tok] = f2b(acc[mi][nj][2] + bb.z);
        bufA[(chb + 3) * EK2 + tok] = f2b(acc[mi][nj][3] + bb.w);
      }
    }
    __syncthreads();

    // ---- ctx GEMM: wave w -> head w. D[kk][vch] = sum_s ek*v (K=128) ----
    f32x4 cacc[2][2];
    #pragma unroll
    for (int mi = 0; mi < 2; ++mi)
      #pragma unroll
      for (int nj = 0; nj < 2; ++nj) cacc[mi][nj] = (f32x4)0.f;
    #pragma unroll
    for (int kc = 0; kc < 4; ++kc) {
      bf16x8 ae[2], bvv[2];
      #pragma unroll
      for (int mi = 0; mi < 2; ++mi)
        ae[mi] = *(const bf16x8*)&ekb[(w * 32 + mi * 16 + l15) * EK2 + kc * 32 + quad * 8];
      #pragma unroll
      for (int nj = 0; nj < 2; ++nj)
        bvv[nj] = *(const bf16x8*)&bufA[(w * 32 + nj * 16 + l15) * EK2 + kc * 32 + quad * 8];
      #pragma unroll
      for (int mi = 0; mi < 2; ++mi)
        #pragma unroll
        for (int nj = 0; nj < 2; ++nj)
          cacc[mi][nj] = mfma16(ae[mi], bvv[nj], cacc[mi][nj]);
    }
    // denominator: threads 0..255 each sum one ek row over 128 tokens
    float dsum = 0.f;
    if (t < 256) {
      #pragma unroll
      for (int s = 0; s < TT; s += 8) {
        u16x8 v = *(const u16x8*)&ekb[t * EK2 + s];
        #pragma unroll
        for (int j = 0; j < 8; ++j) dsum += b2f(v[j]);
      }
    }

    // ---- streaming partial stores (bf16 ctx + fp32 denom) ----
    u16* cp = ctxPart + ((size_t)(b * 64 + g) << 13);
    #pragma unroll
    for (int mi = 0; mi < 2; ++mi)
      #pragma unroll
      for (int nj = 0; nj < 2; ++nj)
        #pragma unroll
        for (int r = 0; r < 4; ++r) {
          int e = ((w * 32 + mi * 16 + quad * 4 + r) << 5) + nj * 16 + l15;
          cp[e] = f2b(cacc[mi][nj][r]);
        }
    if (t < 256)
      denomPart[(size_t)(b * 64 + g) * 256 + t] = dsum;
  }

  grid_sync(&cnt[0], t);

  // ======================= Phase B: reduction =============================
  {
    const int gid = blockIdx.x * 512 + t;
    if (gid < 32768) {
      const int b2 = gid >> 13, e = gid & 8191;
      const u16* p = ctxPart + (((size_t)b2 * 64) << 13) + e;
      float s0 = 0.f, s1 = 0.f, s2 = 0.f, s3 = 0.f;
      #pragma unroll 4
      for (int g2 = 0; g2 < 64; g2 += 4) {
        s0 += b2f(p[(size_t)(g2 + 0) << 13]);
        s1 += b2f(p[(size_t)(g2 + 1) << 13]);
        s2 += b2f(p[(size_t)(g2 + 2) << 13]);
        s3 += b2f(p[(size_t)(g2 + 3) << 13]);
      }
      float s = (s0 + s1) + (s2 + s3);
      int hh = e >> 10, kk = (e >> 5) & 31, vch = e & 31;
      ctxT[(((b2 * 8 + hh) * 32 + vch) << 5) + kk] = f2b(s);
    } else if (gid < 33792) {
      int j = gid - 32768, b2 = j >> 8, ch = j & 255;
      const float* p = denomPart + (size_t)(b2 * 64) * 256 + ch;
      float s = 0.f;
      #pragma unroll 8
      for (int g2 = 0; g2 < 64; ++g2) s += p[(size_t)g2 << 8];
      rdenomF[j] = 1.0f / s;
    }
  }

  grid_sync(&cnt[1], t);

  // ======================= Phase C: output ================================
  u16* xs = bufA;   // x tile [tok][XTP]  (33792 u16 <= 34816)
  u16* qs = ekb;    // stage scratch; then qn/att [tok][XTP]

  stage_xtile(xb, qs, xs, t);   // L3-warm re-read
  __syncthreads();   // xs ready; qs scratch reads done

  // ---- ctx A-frags from bf16 ctxT (first touch this phase; L2-hot) ----
  bf16x8 ac[2];
  #pragma unroll
  for (int mi = 0; mi < 2; ++mi)
    ac[mi] = *(const bf16x8*)(ctxT + (((size_t)(b * 8 + w) * 32 + mi * 16 + l15) << 5) + quad * 8);

  f32x4 acc[2][8];
  // ---- Q GEMM: wave w -> och [32w, 32w+32) == head w ----
  #pragma unroll
  for (int mi = 0; mi < 2; ++mi)
    #pragma unroll
    for (int nj = 0; nj < 8; ++nj) acc[mi][nj] = (f32x4)0.f;
  for (int k0 = 0; k0 < NCH; k0 += 32) {
    bf16x8 af[2], bx[8];
    #pragma unroll
    for (int mi = 0; mi < 2; ++mi)
      af[mi] = *(const bf16x8*)(Wqb + (size_t)(w * 32 + mi * 16 + l15) * NCH + k0 + quad * 8);
    #pragma unroll
    for (int nj = 0; nj < 8; ++nj)
      bx[nj] = *(const bf16x8*)&xs[(nj * 16 + l15) * XTP + k0 + quad * 8];
    #pragma unroll
    for (int mi = 0; mi < 2; ++mi)
      #pragma unroll
      for (int nj = 0; nj < 8; ++nj) acc[mi][nj] = mfma16(af[mi], bx[nj], acc[mi][nj]);
  }
  // bias + exp (in place)
  #pragma unroll
  for (int mi = 0; mi < 2; ++mi) {
    float4 bb = *(const float4*)(bq + w * 32 + mi * 16 + quad * 4);
    #pragma unroll
    for (int nj = 0; nj < 8; ++nj) {
      acc[mi][nj][0] = __expf(acc[mi][nj][0] + bb.x);
      acc[mi][nj][1] = __expf(acc[mi][nj][1] + bb.y);
      acc[mi][nj][2] = __expf(acc[mi][nj][2] + bb.z);
      acc[mi][nj][3] = __expf(acc[mi][nj][3] + bb.w);
    }
  }
  // per-(head, token) softmax denom: in-lane sum + quad reduction
  float inv[8];
  #pragma unroll
  for (int nj = 0; nj < 8; ++nj) {
    float s = 0.f;
    #pragma unroll
    for (int mi = 0; mi < 2; ++mi)
      #pragma unroll
      for (int r = 0; r < 4; ++r) s += acc[mi][nj][r];
    s += __shfl_xor(s, 16);
    s += __shfl_xor(s, 32);
    inv[nj] = 1.0f / s;
  }
  // qn = e * inv * rdenom -> qs [tok][ch], packed b64 writes
  #pragma unroll
  for (int mi = 0; mi < 2; ++mi) {
    float4 rd = *(const float4*)(rdenomF + b * 256 + w * 32 + mi * 16 + quad * 4);
    #pragma unroll
    for (int nj = 0; nj < 8; ++nj) {
      u16x4 pk;
      pk[0] = f2b(acc[mi][nj][0] * inv[nj] * rd.x);
      pk[1] = f2b(acc[mi][nj][1] * inv[nj] * rd.y);
      pk[2] = f2b(acc[mi][nj][2] * inv[nj] * rd.z);
      pk[3] = f2b(acc[mi][nj][3] * inv[nj] * rd.w);
      *(u16x4*)&qs[(nj * 16 + l15) * XTP + w * 32 + mi * 16 + quad * 4] = pk;
    }
  }
  __syncthreads();

  // ---- att GEMM: wave w -> head w; D[vch][tok]; K=32 (one step) ----
  f32x4 aacc[2][8];
  {
    #pragma unroll
    for (int nj = 0; nj < 8; ++nj) {
      bf16x8 bqf = *(const bf16x8*)&qs[(nj * 16 + l15) * XTP + w * 32 + quad * 8];
      #pragma unroll
      for (int mi = 0; mi < 2; ++mi)
        aacc[mi][nj] = mfma16(ac[mi], bqf, (f32x4)0.f);
    }
  }
  // write att over qs (each wave writes exactly the columns only it read)
  #pragma unroll
  for (int mi = 0; mi < 2; ++mi)
    #pragma unroll
    for (int nj = 0; nj < 8; ++nj) {
      u16x4 pk;
      pk[0] = f2b(aacc[mi][nj][0]);
      pk[1] = f2b(aacc[mi][nj][1]);
      pk[2] = f2b(aacc[mi][nj][2]);
      pk[3] = f2b(aacc[mi][nj][3]);
      *(u16x4*)&qs[(nj * 16 + l15) * XTP + w * 32 + mi * 16 + quad * 4] = pk;
    }
  __syncthreads();

  // ---- Wr GEMM ----
  #pragma unroll
  for (int mi = 0; mi < 2; ++mi)
    #pragma unroll
    for (int nj = 0; nj < 8; ++nj) acc[mi][nj] = (f32x4)0.f;
  for (int k0 = 0; k0 < NCH; k0 += 32) {
    bf16x8 af[2], bx[8];
    #pragma unroll
    for (int mi = 0; mi < 2; ++mi)
      af[mi] = *(const bf16x8*)(Wrb + (size_t)(w * 32 + mi * 16 + l15) * NCH + k0 + quad * 8);
    #pragma unroll
    for (int nj = 0; nj < 8; ++nj)
      bx[nj] = *(const bf16x8*)&qs[(nj * 16 + l15) * XTP + k0 + quad * 8];
    #pragma unroll
    for (int mi = 0; mi < 2; ++mi)
      #pragma unroll
      for (int nj = 0; nj < 8; ++nj) acc[mi][nj] = mfma16(af[mi], bx[nj], acc[mi][nj]);
  }
  // bias + residual + transposed float4 store
  #pragma unroll
  for (int mi = 0; mi < 2; ++mi) {
    float4 bb = *(const float4*)(br + w * 32 + mi * 16 + quad * 4);
    #pragma unroll
    for (int nj = 0; nj < 8; ++nj) {
      int tok = nj * 16 + l15;
      u16x4 rx = *(const u16x4*)&xs[tok * XTP + w * 32 + mi * 16 + quad * 4];
      float4 o;
      o.x = acc[mi][nj][0] + bb.x + b2f(rx[0]);
      o.y = acc[mi][nj][1] + bb.y + b2f(rx[1]);
      o.z = acc[mi][nj][2] + bb.z + b2f(rx[2]);
      o.w = acc[mi][nj][3] + bb.w + b2f(rx[3]);
      *(float4*)(out + (((size_t)(b * NTOK + g * TT + tok)) << 8) + w * 32 + mi * 16 + quad * 4) = o;
    }
  }
}

extern "C" void kernel_launch(void* const* d_in, const int* in_sizes, int n_in,
                              void* d_out, int out_size, void* d_ws, size_t ws_size,
                              hipStream_t stream) {
  const float* x  = (const float*)d_in[0];
  const float* Wk = (const float*)d_in[1];
  const float* bk = (const float*)d_in[2];
  const float* Wq = (const float*)d_in[3];
  const float* bq = (const float*)d_in[4];
  const float* Wv = (const float*)d_in[5];
  const float* bv = (const float*)d_in[6];
  const float* Wr = (const float*)d_in[7];
  const float* br = (const float*)d_in[8];
  float* out = (float*)d_out;

  // ws layout (~5 MB total)
  char* wsb = (char*)d_ws;
  u16*      ctxPart   = (u16*)wsb;                      // 256*8192 u16  = 4 MB
  float*    denomPart = (float*)(wsb + 4194304);        // 256*256 f32   = 256 KB
  u16*      ctxT      = (u16*)(wsb + 4456448);          // 32768 u16     = 64 KB
  float*    rdenomF   = (float*)(wsb + 4521984);        // 1024 f32      = 4 KB
  u16*      wbf       = (u16*)(wsb + 4526080);          // 4*65536 u16   = 0.5 MB
  unsigned* cnt       = (unsigned*)(wsb + 5050368);     // 2 u32 grid-sync counters

  hipLaunchKernelGGL(k_prep, dim3(64), dim3(256), 0, stream,
                     Wk, Wq, Wv, Wr, wbf, cnt);
  hipLaunchKernelGGL(k_main, dim3(NBLK), dim3(512), 0, stream,
                     x, wbf, bk, bv, bq, br,
                     ctxPart, denomPart, ctxT, rdenomF, out, cnt);
}

// Round 13
// 148.178 us; speedup vs baseline: 1.2509x; 1.2509x over previous
//
#include <hip/hip_runtime.h>
#include <hip/hip_bf16.h>

#define NTOK 8192
#define NCH  256
#define TT   128         // tokens per tile
#define XTP  264         // stride (u16) for [tok][ch] LDS tiles (16B-aligned rows)
#define EK2  136         // stride (u16) for [ch][tok] LDS tiles (16B-aligned rows)

typedef unsigned short u16;
typedef __attribute__((ext_vector_type(8))) short bf16x8;   // MFMA A/B frag (4 VGPR)
typedef __attribute__((ext_vector_type(4))) float f32x4;    // MFMA C/D frag
typedef __attribute__((ext_vector_type(8))) unsigned short u16x8;
typedef __attribute__((ext_vector_type(4))) unsigned short u16x4;

// Hardware bf16 conversions (RNE, v_cvt path) — r10-verified
__device__ __forceinline__ float b2f(u16 v){
  union { u16 u; __hip_bfloat16 h; } c; c.u = v; return __bfloat162float(c.h);
}
__device__ __forceinline__ u16 f2b(float f){
  union { __hip_bfloat16 h; u16 u; } c; c.h = __float2bfloat16(f); return c.u;
}
__device__ __forceinline__ f32x4 mfma16(bf16x8 a, bf16x8 b, f32x4 c){
  return __builtin_amdgcn_mfma_f32_16x16x32_bf16(a, b, c, 0, 0, 0);
}

// ---------------------------------------------------------------------------
// stage_xtile: global fp32 x tile [256 ch][128 tok] -> bf16 LDS dst [tok][XTP]
// via scratch [ch][EK2]. 1024 threads. One internal barrier; caller MUST
// __syncthreads() after return before reading dst or overwriting scratch.
// (1024-thread variant of the r11-verified TT=128 stage)
// ---------------------------------------------------------------------------
__device__ __forceinline__ void stage_xtile(const float* __restrict__ xb,
                                            u16* scratch, u16* dst, int t)
{
  #pragma unroll
  for (int i = 0; i < 4; ++i) {
    int slot = i * 1024 + t;             // 4096 slots of 8 tokens
    int ch = slot >> 4;
    int tk = (slot & 15) * 8;
    const float* p = xb + (size_t)ch * NTOK + tk;
    float4 v0 = *(const float4*)p;
    float4 v1 = *(const float4*)(p + 4);
    u16x8 pk;
    pk[0]=f2b(v0.x); pk[1]=f2b(v0.y); pk[2]=f2b(v0.z); pk[3]=f2b(v0.w);
    pk[4]=f2b(v1.x); pk[5]=f2b(v1.y); pk[6]=f2b(v1.z); pk[7]=f2b(v1.w);
    *(u16x8*)&scratch[ch * EK2 + tk] = pk;
  }
  __syncthreads();
  // transpose: scratch[ch][tok] -> dst[tok][ch]
  #pragma unroll
  for (int p2 = 0; p2 < 4; ++p2) {
    int idx = p2 * 1024 + t;             // 0..4095
    int tok = idx & 127;
    int ch = (idx >> 7) * 8;
    u16x8 o;
    #pragma unroll
    for (int j = 0; j < 8; ++j) o[j] = scratch[(ch + j) * EK2 + tok];
    *(u16x8*)&dst[tok * XTP + ch] = o;
  }
}

// ---------------------------------------------------------------------------
// k_prep: convert Wk/Wq/Wv/Wr fp32 -> bf16 row-major into wbf (64 blocks).
// ---------------------------------------------------------------------------
__global__ __launch_bounds__(256)
void k_prep(const float* __restrict__ Wk, const float* __restrict__ Wq,
            const float* __restrict__ Wv, const float* __restrict__ Wr,
            u16* __restrict__ wbf)
{
  const int t = threadIdx.x, bid = blockIdx.x;
  const int mat = bid >> 4;
  const float* src = (mat == 0) ? Wk : (mat == 1) ? Wq : (mat == 2) ? Wv : Wr;
  u16* dst = wbf + mat * 65536;
  const int base = (bid & 15) * 4096 + t * 16;
  #pragma unroll
  for (int i = 0; i < 4; ++i) {
    float4 v = *(const float4*)(src + base + i * 4);
    u16x4 pk; pk[0]=f2b(v.x); pk[1]=f2b(v.y); pk[2]=f2b(v.z); pk[3]=f2b(v.w);
    *(u16x4*)(dst + base + i * 4) = pk;
  }
}

// ---------------------------------------------------------------------------
// k_ctx: 256 blocks x 1024 threads (16 waves; 1 block/CU, 139 KB LDS;
// 4 waves/SIMD). Wave w = (head h=w&7, token-half th=w>>3): r3-shaped
// per-wave GEMMs over och slab [32h,32h+32) x tokens [64th, 64th+64).
// K-GEMM->exp->ekb; V-GEMM->vt; ctx GEMM (kc pair per th) + denom half-row
// sums -> streaming bf16/fp32 partial stores (128 partials/batch).
// ---------------------------------------------------------------------------
__global__ __launch_bounds__(1024, 4)
void k_ctx(const float* __restrict__ x, const u16* __restrict__ wbf,
           const float* __restrict__ bk, const float* __restrict__ bv,
           u16* __restrict__ ctxPart, float* __restrict__ denomPart)
{
  __shared__ u16 bufA[NCH * EK2];   // stage: x tile [128][XTP]; later vt [256][EK2]
  __shared__ u16 ekb[NCH * EK2];    // stage scratch [ch][tok]; later exp(K) [ch][tok]

  const int t = threadIdx.x;
  const int b = blockIdx.x >> 6, g = blockIdx.x & 63;
  const int w = t >> 6, lane = t & 63;
  const int h = w & 7, th = w >> 3;
  const int l15 = lane & 15, quad = lane >> 4;
  const u16* Wkb = wbf;
  const u16* Wvb = wbf + 2 * 65536;

  stage_xtile(x + (size_t)b * NCH * NTOK + g * TT, ekb, bufA, t);
  __syncthreads();   // bufA = x tile ready; ekb scratch reads done

  f32x4 acc[2][4];

  // ---- K GEMM: D[och][tok]; wave: och [32h,32h+32) x tok [64th,64th+64) ----
  #pragma unroll
  for (int mi = 0; mi < 2; ++mi)
    #pragma unroll
    for (int nj = 0; nj < 4; ++nj) acc[mi][nj] = (f32x4)0.f;
  for (int k0 = 0; k0 < NCH; k0 += 32) {
    bf16x8 af[2], bx[4];
    #pragma unroll
    for (int mi = 0; mi < 2; ++mi)
      af[mi] = *(const bf16x8*)(Wkb + (size_t)(h * 32 + mi * 16 + l15) * NCH + k0 + quad * 8);
    #pragma unroll
    for (int nj = 0; nj < 4; ++nj)
      bx[nj] = *(const bf16x8*)&bufA[(th * 64 + nj * 16 + l15) * XTP + k0 + quad * 8];
    #pragma unroll
    for (int mi = 0; mi < 2; ++mi)
      #pragma unroll
      for (int nj = 0; nj < 4; ++nj) acc[mi][nj] = mfma16(af[mi], bx[nj], acc[mi][nj]);
  }
  // epilogue: bias + exp -> ekb [ch][tok] (wave-exclusive (row, col-half)) ----
  #pragma unroll
  for (int mi = 0; mi < 2; ++mi) {
    float4 bb = *(const float4*)(bk + h * 32 + mi * 16 + quad * 4);
    #pragma unroll
    for (int nj = 0; nj < 4; ++nj) {
      int tok = th * 64 + nj * 16 + l15, chb = h * 32 + mi * 16 + quad * 4;
      ekb[(chb + 0) * EK2 + tok] = f2b(__expf(acc[mi][nj][0] + bb.x));
      ekb[(chb + 1) * EK2 + tok] = f2b(__expf(acc[mi][nj][1] + bb.y));
      ekb[(chb + 2) * EK2 + tok] = f2b(__expf(acc[mi][nj][2] + bb.z));
      ekb[(chb + 3) * EK2 + tok] = f2b(__expf(acc[mi][nj][3] + bb.w));
    }
  }

  // ---- V GEMM (re-uses acc regs) ----
  #pragma unroll
  for (int mi = 0; mi < 2; ++mi)
    #pragma unroll
    for (int nj = 0; nj < 4; ++nj) acc[mi][nj] = (f32x4)0.f;
  for (int k0 = 0; k0 < NCH; k0 += 32) {
    bf16x8 af[2], bx[4];
    #pragma unroll
    for (int mi = 0; mi < 2; ++mi)
      af[mi] = *(const bf16x8*)(Wvb + (size_t)(h * 32 + mi * 16 + l15) * NCH + k0 + quad * 8);
    #pragma unroll
    for (int nj = 0; nj < 4; ++nj)
      bx[nj] = *(const bf16x8*)&bufA[(th * 64 + nj * 16 + l15) * XTP + k0 + quad * 8];
    #pragma unroll
    for (int mi = 0; mi < 2; ++mi)
      #pragma unroll
      for (int nj = 0; nj < 4; ++nj) acc[mi][nj] = mfma16(af[mi], bx[nj], acc[mi][nj]);
  }
  __syncthreads();   // all waves done reading x tile; safe to overwrite with vt
  #pragma unroll
  for (int mi = 0; mi < 2; ++mi) {
    float4 bb = *(const float4*)(bv + h * 32 + mi * 16 + quad * 4);
    #pragma unroll
    for (int nj = 0; nj < 4; ++nj) {
      int tok = th * 64 + nj * 16 + l15, chb = h * 32 + mi * 16 + quad * 4;
      bufA[(chb + 0) * EK2 + tok] = f2b(acc[mi][nj][0] + bb.x);
      bufA[(chb + 1) * EK2 + tok] = f2b(acc[mi][nj][1] + bb.y);
      bufA[(chb + 2) * EK2 + tok] = f2b(acc[mi][nj][2] + bb.z);
      bufA[(chb + 3) * EK2 + tok] = f2b(acc[mi][nj][3] + bb.w);
    }
  }
  __syncthreads();

  // ---- ctx GEMM: wave -> head h, kc pair th*2+{0,1}. D[kk][vch] ----
  f32x4 cacc[2][2];
  #pragma unroll
  for (int mi = 0; mi < 2; ++mi)
    #pragma unroll
    for (int nj = 0; nj < 2; ++nj) cacc[mi][nj] = (f32x4)0.f;
  #pragma unroll
  for (int kci = 0; kci < 2; ++kci) {
    int kc = th * 2 + kci;
    bf16x8 ae[2], bvv[2];
    #pragma unroll
    for (int mi = 0; mi < 2; ++mi)
      ae[mi] = *(const bf16x8*)&ekb[(h * 32 + mi * 16 + l15) * EK2 + kc * 32 + quad * 8];
    #pragma unroll
    for (int nj = 0; nj < 2; ++nj)
      bvv[nj] = *(const bf16x8*)&bufA[(h * 32 + nj * 16 + l15) * EK2 + kc * 32 + quad * 8];
    #pragma unroll
    for (int mi = 0; mi < 2; ++mi)
      #pragma unroll
      for (int nj = 0; nj < 2; ++nj)
        cacc[mi][nj] = mfma16(ae[mi], bvv[nj], cacc[mi][nj]);
  }
  // denominator: threads 0..511, thread sums ch over its 64-token half
  float dsum = 0.f;
  if (t < 512) {
    int ch = t & 255, th2 = t >> 8;
    #pragma unroll
    for (int s = 0; s < 64; s += 8) {
      u16x8 v = *(const u16x8*)&ekb[ch * EK2 + th2 * 64 + s];
      #pragma unroll
      for (int j = 0; j < 8; ++j) dsum += b2f(v[j]);
    }
  }

  // ---- streaming partial stores: slot = b*128 + g*2 + th ----
  u16* cp = ctxPart + ((size_t)(b * 128 + g * 2 + th) << 13);
  #pragma unroll
  for (int mi = 0; mi < 2; ++mi)
    #pragma unroll
    for (int nj = 0; nj < 2; ++nj)
      #pragma unroll
      for (int r = 0; r < 4; ++r) {
        int e = ((h * 32 + mi * 16 + quad * 4 + r) << 5) + nj * 16 + l15;
        cp[e] = f2b(cacc[mi][nj][r]);
      }
  if (t < 512) {
    int ch = t & 255, th2 = t >> 8;
    denomPart[(size_t)(b * 128 + g * 2 + th2) * 256 + ch] = dsum;
  }
}

// ---------------------------------------------------------------------------
// k_red: sum 128 partials -> ctxT bf16 [b][h][vch][kk] (A-operand-ready) and
// rdenomF = 1/denom fp32 [b][256]  (exact r3 kernel, verified)
// ---------------------------------------------------------------------------
__global__ __launch_bounds__(256)
void k_red(const u16* __restrict__ ctxPart, const float* __restrict__ denomPart,
           u16* __restrict__ ctxT, float* __restrict__ rdenomF)
{
  int i = blockIdx.x * 256 + threadIdx.x;
  if (i < 32768) {
    int b = i >> 13, e = i & 8191;
    const u16* p = ctxPart + ((size_t)(b * 128) << 13) + e;
    float s0 = 0.f, s1 = 0.f, s2 = 0.f, s3 = 0.f;
    #pragma unroll 8
    for (int g = 0; g < 128; g += 4) {
      s0 += b2f(p[(size_t)(g + 0) << 13]);
      s1 += b2f(p[(size_t)(g + 1) << 13]);
      s2 += b2f(p[(size_t)(g + 2) << 13]);
      s3 += b2f(p[(size_t)(g + 3) << 13]);
    }
    float s = (s0 + s1) + (s2 + s3);
    int hh = e >> 10, kk = (e >> 5) & 31, vch = e & 31;
    ctxT[(((b * 8 + hh) * 32 + vch) << 5) + kk] = f2b(s);
  } else if (i < 33792) {
    int j = i - 32768, b = j >> 8, ch = j & 255;
    const float* p = denomPart + (size_t)(b * 128) * 256 + ch;
    float s = 0.f;
    #pragma unroll 8
    for (int g = 0; g < 128; ++g) s += p[(size_t)g << 8];
    rdenomF[j] = 1.0f / s;
  }
}

// ---------------------------------------------------------------------------
// k_out: 256 blocks x 1024 threads (16 waves; 1 block/CU, 137 KB LDS).
// Wave w = (head h=w&7, token-half th=w>>3). In-LDS x stage; Q-GEMM->exp->
// head softmax * rdenom -> qn LDS [tok][ch]; att GEMM (A=ctxT, out aliased
// over qn, wave-exclusive regions); Wr-GEMM; +bias +bf16 residual; store.
// ---------------------------------------------------------------------------
__global__ __launch_bounds__(1024, 4)
void k_out(const float* __restrict__ x, const u16* __restrict__ wbf,
           const float* __restrict__ bq, const float* __restrict__ br,
           const u16* __restrict__ ctxT, const float* __restrict__ rdenomF,
           float* __restrict__ out)
{
  __shared__ u16 xs[TT * XTP];      // x tile [tok][ch]  (128*264 = 67.6 KB)
  __shared__ u16 qs[NCH * EK2];     // stage scratch [256][EK2]; then qn/att [128][XTP]

  const int t = threadIdx.x;
  const int b = blockIdx.x >> 6, g = blockIdx.x & 63;
  const int w = t >> 6, lane = t & 63;
  const int h = w & 7, th = w >> 3;
  const int l15 = lane & 15, quad = lane >> 4;
  const u16* Wqb = wbf + 65536;
  const u16* Wrb = wbf + 3 * 65536;

  stage_xtile(x + (size_t)b * NCH * NTOK + g * TT, qs, xs, t);
  __syncthreads();   // xs ready; all qs scratch reads done

  // ---- ctx A-frags from bf16 ctxT (A-operand-ready; L2-hot) ----
  bf16x8 ac[2];
  #pragma unroll
  for (int mi = 0; mi < 2; ++mi)
    ac[mi] = *(const bf16x8*)(ctxT + (((size_t)(b * 8 + h) * 32 + mi * 16 + l15) << 5) + quad * 8);

  f32x4 acc[2][4];
  // ---- Q GEMM: wave: och [32h,32h+32) x tok [64th,64th+64) ----
  #pragma unroll
  for (int mi = 0; mi < 2; ++mi)
    #pragma unroll
    for (int nj = 0; nj < 4; ++nj) acc[mi][nj] = (f32x4)0.f;
  for (int k0 = 0; k0 < NCH; k0 += 32) {
    bf16x8 af[2], bx[4];
    #pragma unroll
    for (int mi = 0; mi < 2; ++mi)
      af[mi] = *(const bf16x8*)(Wqb + (size_t)(h * 32 + mi * 16 + l15) * NCH + k0 + quad * 8);
    #pragma unroll
    for (int nj = 0; nj < 4; ++nj)
      bx[nj] = *(const bf16x8*)&xs[(th * 64 + nj * 16 + l15) * XTP + k0 + quad * 8];
    #pragma unroll
    for (int mi = 0; mi < 2; ++mi)
      #pragma unroll
      for (int nj = 0; nj < 4; ++nj) acc[mi][nj] = mfma16(af[mi], bx[nj], acc[mi][nj]);
  }
  // bias + exp (in place)
  #pragma unroll
  for (int mi = 0; mi < 2; ++mi) {
    float4 bb = *(const float4*)(bq + h * 32 + mi * 16 + quad * 4);
    #pragma unroll
    for (int nj = 0; nj < 4; ++nj) {
      acc[mi][nj][0] = __expf(acc[mi][nj][0] + bb.x);
      acc[mi][nj][1] = __expf(acc[mi][nj][1] + bb.y);
      acc[mi][nj][2] = __expf(acc[mi][nj][2] + bb.z);
      acc[mi][nj][3] = __expf(acc[mi][nj][3] + bb.w);
    }
  }
  // per-(head, token) softmax denom: in-lane sum (8 ch) + quad shfl (32 ch)
  float inv[4];
  #pragma unroll
  for (int nj = 0; nj < 4; ++nj) {
    float s = 0.f;
    #pragma unroll
    for (int mi = 0; mi < 2; ++mi)
      #pragma unroll
      for (int r = 0; r < 4; ++r) s += acc[mi][nj][r];
    s += __shfl_xor(s, 16);
    s += __shfl_xor(s, 32);
    inv[nj] = 1.0f / s;
  }
  // qn = e * inv * rdenom -> qs [tok][ch], packed b64 writes
  #pragma unroll
  for (int mi = 0; mi < 2; ++mi) {
    float4 rd = *(const float4*)(rdenomF + b * 256 + h * 32 + mi * 16 + quad * 4);
    #pragma unroll
    for (int nj = 0; nj < 4; ++nj) {
      u16x4 pk;
      pk[0] = f2b(acc[mi][nj][0] * inv[nj] * rd.x);
      pk[1] = f2b(acc[mi][nj][1] * inv[nj] * rd.y);
      pk[2] = f2b(acc[mi][nj][2] * inv[nj] * rd.z);
      pk[3] = f2b(acc[mi][nj][3] * inv[nj] * rd.w);
      *(u16x4*)&qs[(th * 64 + nj * 16 + l15) * XTP + h * 32 + mi * 16 + quad * 4] = pk;
    }
  }
  __syncthreads();

  // ---- att GEMM: wave -> head h, its token half; D[vch][tok]; K=32 ----
  f32x4 aacc[2][4];
  {
    #pragma unroll
    for (int nj = 0; nj < 4; ++nj) {
      bf16x8 bqf = *(const bf16x8*)&qs[(th * 64 + nj * 16 + l15) * XTP + h * 32 + quad * 8];
      #pragma unroll
      for (int mi = 0; mi < 2; ++mi)
        aacc[mi][nj] = mfma16(ac[mi], bqf, (f32x4)0.f);
    }
  }
  // write att over qs (each wave writes exactly the region only it read)
  #pragma unroll
  for (int mi = 0; mi < 2; ++mi)
    #pragma unroll
    for (int nj = 0; nj < 4; ++nj) {
      u16x4 pk;
      pk[0] = f2b(aacc[mi][nj][0]);
      pk[1] = f2b(aacc[mi][nj][1]);
      pk[2] = f2b(aacc[mi][nj][2]);
      pk[3] = f2b(aacc[mi][nj][3]);
      *(u16x4*)&qs[(th * 64 + nj * 16 + l15) * XTP + h * 32 + mi * 16 + quad * 4] = pk;
    }
  __syncthreads();

  // ---- Wr GEMM ----
  #pragma unroll
  for (int mi = 0; mi < 2; ++mi)
    #pragma unroll
    for (int nj = 0; nj < 4; ++nj) acc[mi][nj] = (f32x4)0.f;
  for (int k0 = 0; k0 < NCH; k0 += 32) {
    bf16x8 af[2], bx[4];
    #pragma unroll
    for (int mi = 0; mi < 2; ++mi)
      af[mi] = *(const bf16x8*)(Wrb + (size_t)(h * 32 + mi * 16 + l15) * NCH + k0 + quad * 8);
    #pragma unroll
    for (int nj = 0; nj < 4; ++nj)
      bx[nj] = *(const bf16x8*)&qs[(th * 64 + nj * 16 + l15) * XTP + k0 + quad * 8];
    #pragma unroll
    for (int mi = 0; mi < 2; ++mi)
      #pragma unroll
      for (int nj = 0; nj < 4; ++nj) acc[mi][nj] = mfma16(af[mi], bx[nj], acc[mi][nj]);
  }
  // bias + residual + transposed float4 store
  #pragma unroll
  for (int mi = 0; mi < 2; ++mi) {
    float4 bb = *(const float4*)(br + h * 32 + mi * 16 + quad * 4);
    #pragma unroll
    for (int nj = 0; nj < 4; ++nj) {
      int tok = th * 64 + nj * 16 + l15;
      u16x4 rx = *(const u16x4*)&xs[tok * XTP + h * 32 + mi * 16 + quad * 4];
      float4 o;
      o.x = acc[mi][nj][0] + bb.x + b2f(rx[0]);
      o.y = acc[mi][nj][1] + bb.y + b2f(rx[1]);
      o.z = acc[mi][nj][2] + bb.z + b2f(rx[2]);
      o.w = acc[mi][nj][3] + bb.w + b2f(rx[3]);
      *(float4*)(out + (((size_t)(b * NTOK + g * TT + tok)) << 8) + h * 32 + mi * 16 + quad * 4) = o;
    }
  }
}

extern "C" void kernel_launch(void* const* d_in, const int* in_sizes, int n_in,
                              void* d_out, int out_size, void* d_ws, size_t ws_size,
                              hipStream_t stream) {
  const float* x  = (const float*)d_in[0];
  const float* Wk = (const float*)d_in[1];
  const float* bk = (const float*)d_in[2];
  const float* Wq = (const float*)d_in[3];
  const float* bq = (const float*)d_in[4];
  const float* Wv = (const float*)d_in[5];
  const float* bv = (const float*)d_in[6];
  const float* Wr = (const float*)d_in[7];
  const float* br = (const float*)d_in[8];
  float* out = (float*)d_out;

  // ws layout (~9.1 MB total)
  char* wsb = (char*)d_ws;
  u16*   ctxPart   = (u16*)wsb;                         // 512*8192 u16  = 8 MB
  float* denomPart = (float*)(wsb + 8388608);           // 512*256 f32   = 0.5 MB
  u16*   ctxT      = (u16*)(wsb + 8912896);             // 32768 u16     = 64 KB
  float* rdenomF   = (float*)(wsb + 8978432);           // 1024 f32      = 4 KB
  u16*   wbf       = (u16*)(wsb + 8982528);             // 4*65536 u16   = 0.5 MB

  hipLaunchKernelGGL(k_prep, dim3(64), dim3(256), 0, stream,
                     Wk, Wq, Wv, Wr, wbf);
  hipLaunchKernelGGL(k_ctx, dim3(256), dim3(1024), 0, stream,
                     x, wbf, bk, bv, ctxPart, denomPart);
  hipLaunchKernelGGL(k_red, dim3(132), dim3(256), 0, stream,
                     ctxPart, denomPart, ctxT, rdenomF);
  hipLaunchKernelGGL(k_out, dim3(256), dim3(1024), 0, stream,
                     x, wbf, bq, br, ctxT, rdenomF, out);
}

// Round 14
// 144.073 us; speedup vs baseline: 1.2865x; 1.0285x over previous
//
#include <hip/hip_runtime.h>
#include <hip/hip_bf16.h>

#define NTOK 8192
#define NCH  256
#define TT   128         // tokens per tile
#define XTP  264         // stride (u16) for [tok][ch] LDS tiles (16B-aligned rows)
#define EK2  136         // stride (u16) for [ch][tok] LDS tiles (16B-aligned rows)

typedef unsigned short u16;
typedef __attribute__((ext_vector_type(8))) short bf16x8;   // MFMA A/B frag (4 VGPR)
typedef __attribute__((ext_vector_type(4))) float f32x4;    // MFMA C/D frag
typedef __attribute__((ext_vector_type(8))) unsigned short u16x8;
typedef __attribute__((ext_vector_type(4))) unsigned short u16x4;

// Hardware bf16 conversions (RNE, v_cvt path) — r10-verified
__device__ __forceinline__ float b2f(u16 v){
  union { u16 u; __hip_bfloat16 h; } c; c.u = v; return __bfloat162float(c.h);
}
__device__ __forceinline__ u16 f2b(float f){
  union { __hip_bfloat16 h; u16 u; } c; c.h = __float2bfloat16(f); return c.u;
}
__device__ __forceinline__ f32x4 mfma16(bf16x8 a, bf16x8 b, f32x4 c){
  return __builtin_amdgcn_mfma_f32_16x16x32_bf16(a, b, c, 0, 0, 0);
}

// ---------------------------------------------------------------------------
// stage_xtile: global fp32 x tile [256 ch][128 tok] -> bf16 LDS dst [tok][XTP]
// via scratch [ch][EK2]. 512 threads. One internal barrier; caller MUST
// __syncthreads() after return before reading dst or overwriting scratch.
// (r11-verified TT=128 stage)
// ---------------------------------------------------------------------------
__device__ __forceinline__ void stage_xtile(const float* __restrict__ xb,
                                            u16* scratch, u16* dst, int t)
{
  #pragma unroll
  for (int i = 0; i < 8; ++i) {
    int ch = i * 32 + (t >> 4);          // 32 ch rows per iteration
    int tk = (t & 15) * 8;               // 8 consecutive tokens
    const float* p = xb + (size_t)ch * NTOK + tk;
    float4 v0 = *(const float4*)p;
    float4 v1 = *(const float4*)(p + 4);
    u16x8 pk;
    pk[0]=f2b(v0.x); pk[1]=f2b(v0.y); pk[2]=f2b(v0.z); pk[3]=f2b(v0.w);
    pk[4]=f2b(v1.x); pk[5]=f2b(v1.y); pk[6]=f2b(v1.z); pk[7]=f2b(v1.w);
    *(u16x8*)&scratch[ch * EK2 + tk] = pk;
  }
  __syncthreads();
  // transpose: scratch[ch][tok] -> dst[tok][ch]
  #pragma unroll
  for (int p2 = 0; p2 < 8; ++p2) {
    int idx = p2 * 512 + t;              // 0..4095
    int tok = idx & 127;
    int ch = (idx >> 7) * 8;
    u16x8 o;
    #pragma unroll
    for (int j = 0; j < 8; ++j) o[j] = scratch[(ch + j) * EK2 + tok];
    *(u16x8*)&dst[tok * XTP + ch] = o;
  }
}

// ---------------------------------------------------------------------------
// k_prep: convert Wk/Wq/Wv/Wr fp32 -> bf16 row-major into wbf (64 blocks).
// ---------------------------------------------------------------------------
__global__ __launch_bounds__(256)
void k_prep(const float* __restrict__ Wk, const float* __restrict__ Wq,
            const float* __restrict__ Wv, const float* __restrict__ Wr,
            u16* __restrict__ wbf)
{
  const int t = threadIdx.x, bid = blockIdx.x;
  const int mat = bid >> 4;
  const float* src = (mat == 0) ? Wk : (mat == 1) ? Wq : (mat == 2) ? Wv : Wr;
  u16* dst = wbf + mat * 65536;
  const int base = (bid & 15) * 4096 + t * 16;
  #pragma unroll
  for (int i = 0; i < 4; ++i) {
    float4 v = *(const float4*)(src + base + i * 4);
    u16x4 pk; pk[0]=f2b(v.x); pk[1]=f2b(v.y); pk[2]=f2b(v.z); pk[3]=f2b(v.w);
    *(u16x4*)(dst + base + i * 4) = pk;
  }
}

// ---------------------------------------------------------------------------
// k_ctx: 256 blocks x 512 threads (1 block/CU; 139 KB LDS). Wave w owns
// out-ch slab [32w, 32w+32) == head w. In-LDS x stage; K-GEMM->exp->ekb;
// V-GEMM->vt (aliased over x tile); ctx GEMM (K=128, 4 steps) + denom
// row-sums -> streaming bf16/fp32 partial stores. (r11-verified, unchanged)
// ---------------------------------------------------------------------------
__global__ __launch_bounds__(512, 2)
void k_ctx(const float* __restrict__ x, const u16* __restrict__ wbf,
           const float* __restrict__ bk, const float* __restrict__ bv,
           u16* __restrict__ ctxPart, float* __restrict__ denomPart)
{
  __shared__ u16 bufA[NCH * EK2];   // stage: x tile [128][XTP]; later vt [256][EK2]
  __shared__ u16 ekb[NCH * EK2];    // stage scratch [ch][tok]; later exp(K) [ch][tok]

  const int t = threadIdx.x;
  const int b = blockIdx.x >> 6, g = blockIdx.x & 63;
  const int w = t >> 6, lane = t & 63;
  const int l15 = lane & 15, quad = lane >> 4;
  const u16* Wkb = wbf;
  const u16* Wvb = wbf + 2 * 65536;

  stage_xtile(x + (size_t)b * NCH * NTOK + g * TT, ekb, bufA, t);
  __syncthreads();   // bufA = x tile ready; ekb scratch reads done

  f32x4 acc[2][8];

  // ---- K GEMM: D[och][tok], wave w owns och [32w, 32w+32) ----
  #pragma unroll
  for (int mi = 0; mi < 2; ++mi)
    #pragma unroll
    for (int nj = 0; nj < 8; ++nj) acc[mi][nj] = (f32x4)0.f;
  for (int k0 = 0; k0 < NCH; k0 += 32) {
    bf16x8 af[2], bx[8];
    #pragma unroll
    for (int mi = 0; mi < 2; ++mi)
      af[mi] = *(const bf16x8*)(Wkb + (size_t)(w * 32 + mi * 16 + l15) * NCH + k0 + quad * 8);
    #pragma unroll
    for (int nj = 0; nj < 8; ++nj)
      bx[nj] = *(const bf16x8*)&bufA[(nj * 16 + l15) * XTP + k0 + quad * 8];
    #pragma unroll
    for (int mi = 0; mi < 2; ++mi)
      #pragma unroll
      for (int nj = 0; nj < 8; ++nj) acc[mi][nj] = mfma16(af[mi], bx[nj], acc[mi][nj]);
  }
  // epilogue: bias + exp -> ekb [ch][tok] (wave-exclusive rows)
  #pragma unroll
  for (int mi = 0; mi < 2; ++mi) {
    float4 bb = *(const float4*)(bk + w * 32 + mi * 16 + quad * 4);
    #pragma unroll
    for (int nj = 0; nj < 8; ++nj) {
      int tok = nj * 16 + l15, chb = w * 32 + mi * 16 + quad * 4;
      ekb[(chb + 0) * EK2 + tok] = f2b(__expf(acc[mi][nj][0] + bb.x));
      ekb[(chb + 1) * EK2 + tok] = f2b(__expf(acc[mi][nj][1] + bb.y));
      ekb[(chb + 2) * EK2 + tok] = f2b(__expf(acc[mi][nj][2] + bb.z));
      ekb[(chb + 3) * EK2 + tok] = f2b(__expf(acc[mi][nj][3] + bb.w));
    }
  }

  // ---- V GEMM (re-uses acc regs) ----
  #pragma unroll
  for (int mi = 0; mi < 2; ++mi)
    #pragma unroll
    for (int nj = 0; nj < 8; ++nj) acc[mi][nj] = (f32x4)0.f;
  for (int k0 = 0; k0 < NCH; k0 += 32) {
    bf16x8 af[2], bx[8];
    #pragma unroll
    for (int mi = 0; mi < 2; ++mi)
      af[mi] = *(const bf16x8*)(Wvb + (size_t)(w * 32 + mi * 16 + l15) * NCH + k0 + quad * 8);
    #pragma unroll
    for (int nj = 0; nj < 8; ++nj)
      bx[nj] = *(const bf16x8*)&bufA[(nj * 16 + l15) * XTP + k0 + quad * 8];
    #pragma unroll
    for (int mi = 0; mi < 2; ++mi)
      #pragma unroll
      for (int nj = 0; nj < 8; ++nj) acc[mi][nj] = mfma16(af[mi], bx[nj], acc[mi][nj]);
  }
  __syncthreads();   // all waves done reading x tile; safe to overwrite with vt
  #pragma unroll
  for (int mi = 0; mi < 2; ++mi) {
    float4 bb = *(const float4*)(bv + w * 32 + mi * 16 + quad * 4);
    #pragma unroll
    for (int nj = 0; nj < 8; ++nj) {
      int tok = nj * 16 + l15, chb = w * 32 + mi * 16 + quad * 4;
      bufA[(chb + 0) * EK2 + tok] = f2b(acc[mi][nj][0] + bb.x);
      bufA[(chb + 1) * EK2 + tok] = f2b(acc[mi][nj][1] + bb.y);
      bufA[(chb + 2) * EK2 + tok] = f2b(acc[mi][nj][2] + bb.z);
      bufA[(chb + 3) * EK2 + tok] = f2b(acc[mi][nj][3] + bb.w);
    }
  }
  __syncthreads();

  // ---- ctx GEMM: wave w -> head w. D[kk][vch] = sum_s ek*v (K=128) ----
  f32x4 cacc[2][2];
  #pragma unroll
  for (int mi = 0; mi < 2; ++mi)
    #pragma unroll
    for (int nj = 0; nj < 2; ++nj) cacc[mi][nj] = (f32x4)0.f;
  #pragma unroll
  for (int kc = 0; kc < 4; ++kc) {
    bf16x8 ae[2], bvv[2];
    #pragma unroll
    for (int mi = 0; mi < 2; ++mi)
      ae[mi] = *(const bf16x8*)&ekb[(w * 32 + mi * 16 + l15) * EK2 + kc * 32 + quad * 8];
    #pragma unroll
    for (int nj = 0; nj < 2; ++nj)
      bvv[nj] = *(const bf16x8*)&bufA[(w * 32 + nj * 16 + l15) * EK2 + kc * 32 + quad * 8];
    #pragma unroll
    for (int mi = 0; mi < 2; ++mi)
      #pragma unroll
      for (int nj = 0; nj < 2; ++nj)
        cacc[mi][nj] = mfma16(ae[mi], bvv[nj], cacc[mi][nj]);
  }
  // denominator: threads 0..255 each sum one ek row over 128 tokens
  float dsum = 0.f;
  if (t < 256) {
    #pragma unroll
    for (int s = 0; s < TT; s += 8) {
      u16x8 v = *(const u16x8*)&ekb[t * EK2 + s];
      #pragma unroll
      for (int j = 0; j < 8; ++j) dsum += b2f(v[j]);
    }
  }

  // ---- streaming partial stores (bf16 ctx + fp32 denom, no contention) ----
  u16* cp = ctxPart + ((size_t)(b * 64 + g) << 13);
  #pragma unroll
  for (int mi = 0; mi < 2; ++mi)
    #pragma unroll
    for (int nj = 0; nj < 2; ++nj)
      #pragma unroll
      for (int r = 0; r < 4; ++r) {
        int e = ((w * 32 + mi * 16 + quad * 4 + r) << 5) + nj * 16 + l15;
        cp[e] = f2b(cacc[mi][nj][r]);
      }
  if (t < 256)
    denomPart[(size_t)(b * 64 + g) * 256 + t] = dsum;
}

// ---------------------------------------------------------------------------
// k_out: 256 blocks x 512 threads (1 block/CU; 151 KB LDS). In-LDS x stage;
// INLINE reduction of 64 ctx/denom partials (batch-local, L2-hot) into LDS
// ctxbuf/rdnbuf — overlaps Q-GEMM via wave interleave; Q-GEMM->exp->head
// softmax -> qn = e*inv (rdenom folded into att A-operand, r7-verified);
// att GEMM; Wr-GEMM; +bias +bf16 residual; coalesced float4 store.
// ---------------------------------------------------------------------------
__global__ __launch_bounds__(512, 2)
void k_out(const float* __restrict__ x, const u16* __restrict__ wbf,
           const float* __restrict__ bq, const float* __restrict__ br,
           const u16* __restrict__ ctxPart, const float* __restrict__ denomPart,
           float* __restrict__ out)
{
  __shared__ u16 xs[TT * XTP];       // x tile [tok][ch]   (67.6 KB)
  __shared__ u16 qs[NCH * EK2];      // stage scratch; then qn/att [128][XTP] (69.6 KB)
  __shared__ u16 ctxbuf[8192];       // reduced ctx [h][vch][kk]            (16 KB)
  __shared__ float rdnbuf[256];      // 1/denom per key channel             (1 KB)

  const int t = threadIdx.x;
  const int b = blockIdx.x >> 6, g = blockIdx.x & 63;
  const int w = t >> 6, lane = t & 63;
  const int l15 = lane & 15, quad = lane >> 4;
  const u16* Wqb = wbf + 65536;
  const u16* Wrb = wbf + 3 * 65536;

  stage_xtile(x + (size_t)b * NCH * NTOK + g * TT, qs, xs, t);
  __syncthreads();   // xs ready; all qs scratch reads done

  // ---- inline partial reduction (redundant per block; L2-hot; overlaps
  //      the Q-GEMM below via wave interleave). Same arithmetic as r11's
  //      k_red; destination LDS instead of global. ----
  {
    #pragma unroll
    for (int half = 0; half < 2; ++half) {
      const int e0 = half * 4096 + t * 8;          // 8 consecutive e
      const u16* p = ctxPart + ((size_t)(b * 64) << 13) + e0;
      float s[8];
      #pragma unroll
      for (int j = 0; j < 8; ++j) s[j] = 0.f;
      #pragma unroll 4
      for (int g2 = 0; g2 < 64; ++g2) {
        u16x8 v = *(const u16x8*)(p + ((size_t)g2 << 13));
        #pragma unroll
        for (int j = 0; j < 8; ++j) s[j] += b2f(v[j]);
      }
      // e = kk*32 + vch; dst layout [h][vch][kk_local] (A-operand-ready)
      const int hh = e0 >> 10, kkl = (e0 >> 5) & 31, vch0 = e0 & 31;
      #pragma unroll
      for (int j = 0; j < 8; ++j)
        ctxbuf[((hh * 32 + vch0 + j) << 5) + kkl] = f2b(s[j]);
    }
    if (t < 256) {
      const float* p = denomPart + (size_t)(b * 64) * 256 + t;
      float s = 0.f;
      #pragma unroll 8
      for (int g2 = 0; g2 < 64; ++g2) s += p[(size_t)g2 << 8];
      rdnbuf[t] = 1.0f / s;
    }
  }

  f32x4 acc[2][8];
  // ---- Q GEMM: wave w -> och [32w, 32w+32) == head w ----
  #pragma unroll
  for (int mi = 0; mi < 2; ++mi)
    #pragma unroll
    for (int nj = 0; nj < 8; ++nj) acc[mi][nj] = (f32x4)0.f;
  for (int k0 = 0; k0 < NCH; k0 += 32) {
    bf16x8 af[2], bx[8];
    #pragma unroll
    for (int mi = 0; mi < 2; ++mi)
      af[mi] = *(const bf16x8*)(Wqb + (size_t)(w * 32 + mi * 16 + l15) * NCH + k0 + quad * 8);
    #pragma unroll
    for (int nj = 0; nj < 8; ++nj)
      bx[nj] = *(const bf16x8*)&xs[(nj * 16 + l15) * XTP + k0 + quad * 8];
    #pragma unroll
    for (int mi = 0; mi < 2; ++mi)
      #pragma unroll
      for (int nj = 0; nj < 8; ++nj) acc[mi][nj] = mfma16(af[mi], bx[nj], acc[mi][nj]);
  }
  // bias + exp (in place)
  #pragma unroll
  for (int mi = 0; mi < 2; ++mi) {
    float4 bb = *(const float4*)(bq + w * 32 + mi * 16 + quad * 4);
    #pragma unroll
    for (int nj = 0; nj < 8; ++nj) {
      acc[mi][nj][0] = __expf(acc[mi][nj][0] + bb.x);
      acc[mi][nj][1] = __expf(acc[mi][nj][1] + bb.y);
      acc[mi][nj][2] = __expf(acc[mi][nj][2] + bb.z);
      acc[mi][nj][3] = __expf(acc[mi][nj][3] + bb.w);
    }
  }
  // per-(head, token) softmax denom: in-lane sum + quad reduction
  float inv[8];
  #pragma unroll
  for (int nj = 0; nj < 8; ++nj) {
    float s = 0.f;
    #pragma unroll
    for (int mi = 0; mi < 2; ++mi)
      #pragma unroll
      for (int r = 0; r < 4; ++r) s += acc[mi][nj][r];
    s += __shfl_xor(s, 16);
    s += __shfl_xor(s, 32);
    inv[nj] = 1.0f / s;
  }
  // qn = e * inv -> qs [tok][ch] (rdenom deferred to att A-operand)
  #pragma unroll
  for (int mi = 0; mi < 2; ++mi) {
    #pragma unroll
    for (int nj = 0; nj < 8; ++nj) {
      u16x4 pk;
      pk[0] = f2b(acc[mi][nj][0] * inv[nj]);
      pk[1] = f2b(acc[mi][nj][1] * inv[nj]);
      pk[2] = f2b(acc[mi][nj][2] * inv[nj]);
      pk[3] = f2b(acc[mi][nj][3] * inv[nj]);
      *(u16x4*)&qs[(nj * 16 + l15) * XTP + w * 32 + mi * 16 + quad * 4] = pk;
    }
  }
  __syncthreads();   // qs ready AND ctxbuf/rdnbuf ready

  // ---- ctx A-frags from LDS, scaled by rdenom along kk (r7-verified) ----
  bf16x8 ac[2];
  {
    float rd[8];
    #pragma unroll
    for (int j = 0; j < 8; ++j) rd[j] = rdnbuf[w * 32 + quad * 8 + j];
    #pragma unroll
    for (int mi = 0; mi < 2; ++mi) {
      #pragma unroll
      for (int j = 0; j < 8; ++j) {
        u16 c = ctxbuf[((w * 32 + mi * 16 + l15) << 5) + quad * 8 + j];
        ac[mi][j] = (short)f2b(b2f(c) * rd[j]);
      }
    }
  }

  // ---- att GEMM: wave w -> head w; D[vch][tok]; K=32 (one step) ----
  f32x4 aacc[2][8];
  {
    #pragma unroll
    for (int nj = 0; nj < 8; ++nj) {
      bf16x8 bqf = *(const bf16x8*)&qs[(nj * 16 + l15) * XTP + w * 32 + quad * 8];
      #pragma unroll
      for (int mi = 0; mi < 2; ++mi)
        aacc[mi][nj] = mfma16(ac[mi], bqf, (f32x4)0.f);
    }
  }
  // write att over qs (each wave writes exactly the columns only it read)
  #pragma unroll
  for (int mi = 0; mi < 2; ++mi)
    #pragma unroll
    for (int nj = 0; nj < 8; ++nj) {
      u16x4 pk;
      pk[0] = f2b(aacc[mi][nj][0]);
      pk[1] = f2b(aacc[mi][nj][1]);
      pk[2] = f2b(aacc[mi][nj][2]);
      pk[3] = f2b(aacc[mi][nj][3]);
      *(u16x4*)&qs[(nj * 16 + l15) * XTP + w * 32 + mi * 16 + quad * 4] = pk;
    }
  __syncthreads();

  // ---- Wr GEMM ----
  #pragma unroll
  for (int mi = 0; mi < 2; ++mi)
    #pragma unroll
    for (int nj = 0; nj < 8; ++nj) acc[mi][nj] = (f32x4)0.f;
  for (int k0 = 0; k0 < NCH; k0 += 32) {
    bf16x8 af[2], bx[8];
    #pragma unroll
    for (int mi = 0; mi < 2; ++mi)
      af[mi] = *(const bf16x8*)(Wrb + (size_t)(w * 32 + mi * 16 + l15) * NCH + k0 + quad * 8);
    #pragma unroll
    for (int nj = 0; nj < 8; ++nj)
      bx[nj] = *(const bf16x8*)&qs[(nj * 16 + l15) * XTP + k0 + quad * 8];
    #pragma unroll
    for (int mi = 0; mi < 2; ++mi)
      #pragma unroll
      for (int nj = 0; nj < 8; ++nj) acc[mi][nj] = mfma16(af[mi], bx[nj], acc[mi][nj]);
  }
  // bias + residual + transposed float4 store
  #pragma unroll
  for (int mi = 0; mi < 2; ++mi) {
    float4 bb = *(const float4*)(br + w * 32 + mi * 16 + quad * 4);
    #pragma unroll
    for (int nj = 0; nj < 8; ++nj) {
      int tok = nj * 16 + l15;
      u16x4 rx = *(const u16x4*)&xs[tok * XTP + w * 32 + mi * 16 + quad * 4];
      float4 o;
      o.x = acc[mi][nj][0] + bb.x + b2f(rx[0]);
      o.y = acc[mi][nj][1] + bb.y + b2f(rx[1]);
      o.z = acc[mi][nj][2] + bb.z + b2f(rx[2]);
      o.w = acc[mi][nj][3] + bb.w + b2f(rx[3]);
      *(float4*)(out + (((size_t)(b * NTOK + g * TT + tok)) << 8) + w * 32 + mi * 16 + quad * 4) = o;
    }
  }
}

extern "C" void kernel_launch(void* const* d_in, const int* in_sizes, int n_in,
                              void* d_out, int out_size, void* d_ws, size_t ws_size,
                              hipStream_t stream) {
  const float* x  = (const float*)d_in[0];
  const float* Wk = (const float*)d_in[1];
  const float* bk = (const float*)d_in[2];
  const float* Wq = (const float*)d_in[3];
  const float* bq = (const float*)d_in[4];
  const float* Wv = (const float*)d_in[5];
  const float* bv = (const float*)d_in[6];
  const float* Wr = (const float*)d_in[7];
  const float* br = (const float*)d_in[8];
  float* out = (float*)d_out;

  // ws layout (~4.9 MB total)
  char* wsb = (char*)d_ws;
  u16*   ctxPart   = (u16*)wsb;                         // 256*8192 u16  = 4 MB
  float* denomPart = (float*)(wsb + 4194304);           // 256*256 f32   = 256 KB
  u16*   wbf       = (u16*)(wsb + 4456448);             // 4*65536 u16   = 0.5 MB

  hipLaunchKernelGGL(k_prep, dim3(64), dim3(256), 0, stream,
                     Wk, Wq, Wv, Wr, wbf);
  hipLaunchKernelGGL(k_ctx, dim3(256), dim3(512), 0, stream,
                     x, wbf, bk, bv, ctxPart, denomPart);
  hipLaunchKernelGGL(k_out, dim3(256), dim3(512), 0, stream,
                     x, wbf, bq, br, ctxPart, denomPart, out);
}

// Round 15
// 133.746 us; speedup vs baseline: 1.3859x; 1.0772x over previous
//
#include <hip/hip_runtime.h>
#include <hip/hip_bf16.h>

#define NTOK 8192
#define NCH  256
#define TT   128         // tokens per tile
#define XTP  264         // stride (u16) for [tok][ch] LDS tiles (16B-aligned rows)
#define EK2  136         // stride (u16) for [ch][tok] LDS tiles (16B-aligned rows)

typedef unsigned short u16;
typedef __attribute__((ext_vector_type(8))) short bf16x8;   // MFMA A/B frag (4 VGPR)
typedef __attribute__((ext_vector_type(4))) float f32x4;    // MFMA C/D frag
typedef __attribute__((ext_vector_type(8))) unsigned short u16x8;
typedef __attribute__((ext_vector_type(4))) unsigned short u16x4;

// Hardware bf16 conversions (RNE, v_cvt path) — r10-verified
__device__ __forceinline__ float b2f(u16 v){
  union { u16 u; __hip_bfloat16 h; } c; c.u = v; return __bfloat162float(c.h);
}
__device__ __forceinline__ u16 f2b(float f){
  union { __hip_bfloat16 h; u16 u; } c; c.h = __float2bfloat16(f); return c.u;
}
__device__ __forceinline__ f32x4 mfma16(bf16x8 a, bf16x8 b, f32x4 c){
  return __builtin_amdgcn_mfma_f32_16x16x32_bf16(a, b, c, 0, 0, 0);
}

// ---------------------------------------------------------------------------
// stage_xtile: global fp32 x tile [256 ch][128 tok] -> bf16 LDS dst [tok][XTP]
// via scratch [ch][EK2]. 512 threads. One internal barrier; caller MUST
// __syncthreads() after return before reading dst or overwriting scratch.
// (r11-verified TT=128 stage)
// ---------------------------------------------------------------------------
__device__ __forceinline__ void stage_xtile(const float* __restrict__ xb,
                                            u16* scratch, u16* dst, int t)
{
  #pragma unroll
  for (int i = 0; i < 8; ++i) {
    int ch = i * 32 + (t >> 4);          // 32 ch rows per iteration
    int tk = (t & 15) * 8;               // 8 consecutive tokens
    const float* p = xb + (size_t)ch * NTOK + tk;
    float4 v0 = *(const float4*)p;
    float4 v1 = *(const float4*)(p + 4);
    u16x8 pk;
    pk[0]=f2b(v0.x); pk[1]=f2b(v0.y); pk[2]=f2b(v0.z); pk[3]=f2b(v0.w);
    pk[4]=f2b(v1.x); pk[5]=f2b(v1.y); pk[6]=f2b(v1.z); pk[7]=f2b(v1.w);
    *(u16x8*)&scratch[ch * EK2 + tk] = pk;
  }
  __syncthreads();
  // transpose: scratch[ch][tok] -> dst[tok][ch]
  #pragma unroll
  for (int p2 = 0; p2 < 8; ++p2) {
    int idx = p2 * 512 + t;              // 0..4095
    int tok = idx & 127;
    int ch = (idx >> 7) * 8;
    u16x8 o;
    #pragma unroll
    for (int j = 0; j < 8; ++j) o[j] = scratch[(ch + j) * EK2 + tok];
    *(u16x8*)&dst[tok * XTP + ch] = o;
  }
}

// ---------------------------------------------------------------------------
// k_prep: convert Wk/Wq/Wv/Wr fp32 -> bf16 row-major into wbf (64 blocks).
// ---------------------------------------------------------------------------
__global__ __launch_bounds__(256)
void k_prep(const float* __restrict__ Wk, const float* __restrict__ Wq,
            const float* __restrict__ Wv, const float* __restrict__ Wr,
            u16* __restrict__ wbf)
{
  const int t = threadIdx.x, bid = blockIdx.x;
  const int mat = bid >> 4;
  const float* src = (mat == 0) ? Wk : (mat == 1) ? Wq : (mat == 2) ? Wv : Wr;
  u16* dst = wbf + mat * 65536;
  const int base = (bid & 15) * 4096 + t * 16;
  #pragma unroll
  for (int i = 0; i < 4; ++i) {
    float4 v = *(const float4*)(src + base + i * 4);
    u16x4 pk; pk[0]=f2b(v.x); pk[1]=f2b(v.y); pk[2]=f2b(v.z); pk[3]=f2b(v.w);
    *(u16x4*)(dst + base + i * 4) = pk;
  }
}

// ---------------------------------------------------------------------------
// k_ctx: 256 blocks x 512 threads (1 block/CU; 139 KB LDS). Wave w owns
// out-ch slab [32w, 32w+32) == head w. In-LDS x stage; K-GEMM->exp->ekb;
// V-GEMM->vt (aliased over x tile); ctx GEMM (K=128, 4 steps) + denom
// row-sums -> streaming bf16/fp32 partial stores. (r11-verified)
// ---------------------------------------------------------------------------
__global__ __launch_bounds__(512, 2)
void k_ctx(const float* __restrict__ x, const u16* __restrict__ wbf,
           const float* __restrict__ bk, const float* __restrict__ bv,
           u16* __restrict__ ctxPart, float* __restrict__ denomPart)
{
  __shared__ u16 bufA[NCH * EK2];   // stage: x tile [128][XTP]; later vt [256][EK2]
  __shared__ u16 ekb[NCH * EK2];    // stage scratch [ch][tok]; later exp(K) [ch][tok]

  const int t = threadIdx.x;
  const int b = blockIdx.x >> 6, g = blockIdx.x & 63;
  const int w = t >> 6, lane = t & 63;
  const int l15 = lane & 15, quad = lane >> 4;
  const u16* Wkb = wbf;
  const u16* Wvb = wbf + 2 * 65536;

  stage_xtile(x + (size_t)b * NCH * NTOK + g * TT, ekb, bufA, t);
  __syncthreads();   // bufA = x tile ready; ekb scratch reads done

  f32x4 acc[2][8];

  // ---- K GEMM: D[och][tok], wave w owns och [32w, 32w+32) ----
  #pragma unroll
  for (int mi = 0; mi < 2; ++mi)
    #pragma unroll
    for (int nj = 0; nj < 8; ++nj) acc[mi][nj] = (f32x4)0.f;
  for (int k0 = 0; k0 < NCH; k0 += 32) {
    bf16x8 af[2], bx[8];
    #pragma unroll
    for (int mi = 0; mi < 2; ++mi)
      af[mi] = *(const bf16x8*)(Wkb + (size_t)(w * 32 + mi * 16 + l15) * NCH + k0 + quad * 8);
    #pragma unroll
    for (int nj = 0; nj < 8; ++nj)
      bx[nj] = *(const bf16x8*)&bufA[(nj * 16 + l15) * XTP + k0 + quad * 8];
    #pragma unroll
    for (int mi = 0; mi < 2; ++mi)
      #pragma unroll
      for (int nj = 0; nj < 8; ++nj) acc[mi][nj] = mfma16(af[mi], bx[nj], acc[mi][nj]);
  }
  // epilogue: bias + exp -> ekb [ch][tok] (wave-exclusive rows)
  #pragma unroll
  for (int mi = 0; mi < 2; ++mi) {
    float4 bb = *(const float4*)(bk + w * 32 + mi * 16 + quad * 4);
    #pragma unroll
    for (int nj = 0; nj < 8; ++nj) {
      int tok = nj * 16 + l15, chb = w * 32 + mi * 16 + quad * 4;
      ekb[(chb + 0) * EK2 + tok] = f2b(__expf(acc[mi][nj][0] + bb.x));
      ekb[(chb + 1) * EK2 + tok] = f2b(__expf(acc[mi][nj][1] + bb.y));
      ekb[(chb + 2) * EK2 + tok] = f2b(__expf(acc[mi][nj][2] + bb.z));
      ekb[(chb + 3) * EK2 + tok] = f2b(__expf(acc[mi][nj][3] + bb.w));
    }
  }

  // ---- V GEMM (re-uses acc regs) ----
  #pragma unroll
  for (int mi = 0; mi < 2; ++mi)
    #pragma unroll
    for (int nj = 0; nj < 8; ++nj) acc[mi][nj] = (f32x4)0.f;
  for (int k0 = 0; k0 < NCH; k0 += 32) {
    bf16x8 af[2], bx[8];
    #pragma unroll
    for (int mi = 0; mi < 2; ++mi)
      af[mi] = *(const bf16x8*)(Wvb + (size_t)(w * 32 + mi * 16 + l15) * NCH + k0 + quad * 8);
    #pragma unroll
    for (int nj = 0; nj < 8; ++nj)
      bx[nj] = *(const bf16x8*)&bufA[(nj * 16 + l15) * XTP + k0 + quad * 8];
    #pragma unroll
    for (int mi = 0; mi < 2; ++mi)
      #pragma unroll
      for (int nj = 0; nj < 8; ++nj) acc[mi][nj] = mfma16(af[mi], bx[nj], acc[mi][nj]);
  }
  __syncthreads();   // all waves done reading x tile; safe to overwrite with vt
  #pragma unroll
  for (int mi = 0; mi < 2; ++mi) {
    float4 bb = *(const float4*)(bv + w * 32 + mi * 16 + quad * 4);
    #pragma unroll
    for (int nj = 0; nj < 8; ++nj) {
      int tok = nj * 16 + l15, chb = w * 32 + mi * 16 + quad * 4;
      bufA[(chb + 0) * EK2 + tok] = f2b(acc[mi][nj][0] + bb.x);
      bufA[(chb + 1) * EK2 + tok] = f2b(acc[mi][nj][1] + bb.y);
      bufA[(chb + 2) * EK2 + tok] = f2b(acc[mi][nj][2] + bb.z);
      bufA[(chb + 3) * EK2 + tok] = f2b(acc[mi][nj][3] + bb.w);
    }
  }
  __syncthreads();

  // ---- ctx GEMM: wave w -> head w. D[kk][vch] = sum_s ek*v (K=128) ----
  f32x4 cacc[2][2];
  #pragma unroll
  for (int mi = 0; mi < 2; ++mi)
    #pragma unroll
    for (int nj = 0; nj < 2; ++nj) cacc[mi][nj] = (f32x4)0.f;
  #pragma unroll
  for (int kc = 0; kc < 4; ++kc) {
    bf16x8 ae[2], bvv[2];
    #pragma unroll
    for (int mi = 0; mi < 2; ++mi)
      ae[mi] = *(const bf16x8*)&ekb[(w * 32 + mi * 16 + l15) * EK2 + kc * 32 + quad * 8];
    #pragma unroll
    for (int nj = 0; nj < 2; ++nj)
      bvv[nj] = *(const bf16x8*)&bufA[(w * 32 + nj * 16 + l15) * EK2 + kc * 32 + quad * 8];
    #pragma unroll
    for (int mi = 0; mi < 2; ++mi)
      #pragma unroll
      for (int nj = 0; nj < 2; ++nj)
        cacc[mi][nj] = mfma16(ae[mi], bvv[nj], cacc[mi][nj]);
  }
  // denominator: threads 0..255 each sum one ek row over 128 tokens
  float dsum = 0.f;
  if (t < 256) {
    #pragma unroll
    for (int s = 0; s < TT; s += 8) {
      u16x8 v = *(const u16x8*)&ekb[t * EK2 + s];
      #pragma unroll
      for (int j = 0; j < 8; ++j) dsum += b2f(v[j]);
    }
  }

  // ---- streaming partial stores (bf16 ctx + fp32 denom, no contention) ----
  u16* cp = ctxPart + ((size_t)(b * 64 + g) << 13);
  #pragma unroll
  for (int mi = 0; mi < 2; ++mi)
    #pragma unroll
    for (int nj = 0; nj < 2; ++nj)
      #pragma unroll
      for (int r = 0; r < 4; ++r) {
        int e = ((w * 32 + mi * 16 + quad * 4 + r) << 5) + nj * 16 + l15;
        cp[e] = f2b(cacc[mi][nj][r]);
      }
  if (t < 256)
    denomPart[(size_t)(b * 64 + g) * 256 + t] = dsum;
}

// ---------------------------------------------------------------------------
// k_red: sum 64 partials -> ctxT bf16 [b][h][vch][kk] (A-operand-ready) and
// rdenomF = 1/denom fp32 [b][256]  (r11-verified)
// ---------------------------------------------------------------------------
__global__ __launch_bounds__(256)
void k_red(const u16* __restrict__ ctxPart, const float* __restrict__ denomPart,
           u16* __restrict__ ctxT, float* __restrict__ rdenomF)
{
  int i = blockIdx.x * 256 + threadIdx.x;
  if (i < 32768) {
    int b = i >> 13, e = i & 8191;
    const u16* p = ctxPart + ((size_t)(b * 64) << 13) + e;
    float s0 = 0.f, s1 = 0.f, s2 = 0.f, s3 = 0.f;
    #pragma unroll 4
    for (int g = 0; g < 64; g += 4) {
      s0 += b2f(p[(size_t)(g + 0) << 13]);
      s1 += b2f(p[(size_t)(g + 1) << 13]);
      s2 += b2f(p[(size_t)(g + 2) << 13]);
      s3 += b2f(p[(size_t)(g + 3) << 13]);
    }
    float s = (s0 + s1) + (s2 + s3);
    int hh = e >> 10, kk = (e >> 5) & 31, vch = e & 31;
    ctxT[(((b * 8 + hh) * 32 + vch) << 5) + kk] = f2b(s);
  } else if (i < 33792) {
    int j = i - 32768, b = j >> 8, ch = j & 255;
    const float* p = denomPart + (size_t)(b * 64) * 256 + ch;
    float s = 0.f;
    #pragma unroll 8
    for (int g = 0; g < 64; ++g) s += p[(size_t)g << 8];
    rdenomF[j] = 1.0f / s;
  }
}

// ---------------------------------------------------------------------------
// k_out: 256 blocks x 512 threads (1 block/CU; 137 KB LDS). In-LDS x stage;
// Q-GEMM->exp->head softmax * rdenom -> qn LDS [tok][ch]; att GEMM (A=ctxT,
// out aliased over qn, wave-exclusive cols); Wr-GEMM; +bias +bf16 residual;
// coalesced float4 store. (r11-verified)
// ---------------------------------------------------------------------------
__global__ __launch_bounds__(512, 2)
void k_out(const float* __restrict__ x, const u16* __restrict__ wbf,
           const float* __restrict__ bq, const float* __restrict__ br,
           const u16* __restrict__ ctxT, const float* __restrict__ rdenomF,
           float* __restrict__ out)
{
  __shared__ u16 xs[TT * XTP];      // x tile [tok][ch]  (128*264 = 67.6 KB)
  __shared__ u16 qs[NCH * EK2];     // stage scratch [256][EK2]; then qn/att [128][XTP]

  const int t = threadIdx.x;
  const int b = blockIdx.x >> 6, g = blockIdx.x & 63;
  const int w = t >> 6, lane = t & 63;
  const int l15 = lane & 15, quad = lane >> 4;
  const u16* Wqb = wbf + 65536;
  const u16* Wrb = wbf + 3 * 65536;

  stage_xtile(x + (size_t)b * NCH * NTOK + g * TT, qs, xs, t);
  __syncthreads();   // xs ready; all qs scratch reads done

  // ---- ctx A-frags from bf16 ctxT (A-operand-ready; L2-hot) ----
  bf16x8 ac[2];
  #pragma unroll
  for (int mi = 0; mi < 2; ++mi)
    ac[mi] = *(const bf16x8*)(ctxT + (((size_t)(b * 8 + w) * 32 + mi * 16 + l15) << 5) + quad * 8);

  f32x4 acc[2][8];
  // ---- Q GEMM: wave w -> och [32w, 32w+32) == head w ----
  #pragma unroll
  for (int mi = 0; mi < 2; ++mi)
    #pragma unroll
    for (int nj = 0; nj < 8; ++nj) acc[mi][nj] = (f32x4)0.f;
  for (int k0 = 0; k0 < NCH; k0 += 32) {
    bf16x8 af[2], bx[8];
    #pragma unroll
    for (int mi = 0; mi < 2; ++mi)
      af[mi] = *(const bf16x8*)(Wqb + (size_t)(w * 32 + mi * 16 + l15) * NCH + k0 + quad * 8);
    #pragma unroll
    for (int nj = 0; nj < 8; ++nj)
      bx[nj] = *(const bf16x8*)&xs[(nj * 16 + l15) * XTP + k0 + quad * 8];
    #pragma unroll
    for (int mi = 0; mi < 2; ++mi)
      #pragma unroll
      for (int nj = 0; nj < 8; ++nj) acc[mi][nj] = mfma16(af[mi], bx[nj], acc[mi][nj]);
  }
  // bias + exp (in place)
  #pragma unroll
  for (int mi = 0; mi < 2; ++mi) {
    float4 bb = *(const float4*)(bq + w * 32 + mi * 16 + quad * 4);
    #pragma unroll
    for (int nj = 0; nj < 8; ++nj) {
      acc[mi][nj][0] = __expf(acc[mi][nj][0] + bb.x);
      acc[mi][nj][1] = __expf(acc[mi][nj][1] + bb.y);
      acc[mi][nj][2] = __expf(acc[mi][nj][2] + bb.z);
      acc[mi][nj][3] = __expf(acc[mi][nj][3] + bb.w);
    }
  }
  // per-(head, token) softmax denom: in-lane sum + quad reduction
  float inv[8];
  #pragma unroll
  for (int nj = 0; nj < 8; ++nj) {
    float s = 0.f;
    #pragma unroll
    for (int mi = 0; mi < 2; ++mi)
      #pragma unroll
      for (int r = 0; r < 4; ++r) s += acc[mi][nj][r];
    s += __shfl_xor(s, 16);
    s += __shfl_xor(s, 32);
    inv[nj] = 1.0f / s;
  }
  // qn = e * inv * rdenom -> qs [tok][ch], packed b64 writes
  #pragma unroll
  for (int mi = 0; mi < 2; ++mi) {
    float4 rd = *(const float4*)(rdenomF + b * 256 + w * 32 + mi * 16 + quad * 4);
    #pragma unroll
    for (int nj = 0; nj < 8; ++nj) {
      u16x4 pk;
      pk[0] = f2b(acc[mi][nj][0] * inv[nj] * rd.x);
      pk[1] = f2b(acc[mi][nj][1] * inv[nj] * rd.y);
      pk[2] = f2b(acc[mi][nj][2] * inv[nj] * rd.z);
      pk[3] = f2b(acc[mi][nj][3] * inv[nj] * rd.w);
      *(u16x4*)&qs[(nj * 16 + l15) * XTP + w * 32 + mi * 16 + quad * 4] = pk;
    }
  }
  __syncthreads();

  // ---- att GEMM: wave w -> head w; D[vch][tok]; K=32 (one step) ----
  f32x4 aacc[2][8];
  {
    #pragma unroll
    for (int nj = 0; nj < 8; ++nj) {
      bf16x8 bqf = *(const bf16x8*)&qs[(nj * 16 + l15) * XTP + w * 32 + quad * 8];
      #pragma unroll
      for (int mi = 0; mi < 2; ++mi)
        aacc[mi][nj] = mfma16(ac[mi], bqf, (f32x4)0.f);
    }
  }
  // write att over qs (each wave writes exactly the columns only it read)
  #pragma unroll
  for (int mi = 0; mi < 2; ++mi)
    #pragma unroll
    for (int nj = 0; nj < 8; ++nj) {
      u16x4 pk;
      pk[0] = f2b(aacc[mi][nj][0]);
      pk[1] = f2b(aacc[mi][nj][1]);
      pk[2] = f2b(aacc[mi][nj][2]);
      pk[3] = f2b(aacc[mi][nj][3]);
      *(u16x4*)&qs[(nj * 16 + l15) * XTP + w * 32 + mi * 16 + quad * 4] = pk;
    }
  __syncthreads();

  // ---- Wr GEMM ----
  #pragma unroll
  for (int mi = 0; mi < 2; ++mi)
    #pragma unroll
    for (int nj = 0; nj < 8; ++nj) acc[mi][nj] = (f32x4)0.f;
  for (int k0 = 0; k0 < NCH; k0 += 32) {
    bf16x8 af[2], bx[8];
    #pragma unroll
    for (int mi = 0; mi < 2; ++mi)
      af[mi] = *(const bf16x8*)(Wrb + (size_t)(w * 32 + mi * 16 + l15) * NCH + k0 + quad * 8);
    #pragma unroll
    for (int nj = 0; nj < 8; ++nj)
      bx[nj] = *(const bf16x8*)&qs[(nj * 16 + l15) * XTP + k0 + quad * 8];
    #pragma unroll
    for (int mi = 0; mi < 2; ++mi)
      #pragma unroll
      for (int nj = 0; nj < 8; ++nj) acc[mi][nj] = mfma16(af[mi], bx[nj], acc[mi][nj]);
  }
  // bias + residual + transposed float4 store
  #pragma unroll
  for (int mi = 0; mi < 2; ++mi) {
    float4 bb = *(const float4*)(br + w * 32 + mi * 16 + quad * 4);
    #pragma unroll
    for (int nj = 0; nj < 8; ++nj) {
      int tok = nj * 16 + l15;
      u16x4 rx = *(const u16x4*)&xs[tok * XTP + w * 32 + mi * 16 + quad * 4];
      float4 o;
      o.x = acc[mi][nj][0] + bb.x + b2f(rx[0]);
      o.y = acc[mi][nj][1] + bb.y + b2f(rx[1]);
      o.z = acc[mi][nj][2] + bb.z + b2f(rx[2]);
      o.w = acc[mi][nj][3] + bb.w + b2f(rx[3]);
      *(float4*)(out + (((size_t)(b * NTOK + g * TT + tok)) << 8) + w * 32 + mi * 16 + quad * 4) = o;
    }
  }
}

extern "C" void kernel_launch(void* const* d_in, const int* in_sizes, int n_in,
                              void* d_out, int out_size, void* d_ws, size_t ws_size,
                              hipStream_t stream) {
  const float* x  = (const float*)d_in[0];
  const float* Wk = (const float*)d_in[1];
  const float* bk = (const float*)d_in[2];
  const float* Wq = (const float*)d_in[3];
  const float* bq = (const float*)d_in[4];
  const float* Wv = (const float*)d_in[5];
  const float* bv = (const float*)d_in[6];
  const float* Wr = (const float*)d_in[7];
  const float* br = (const float*)d_in[8];
  float* out = (float*)d_out;

  // ws layout (~5 MB total)
  char* wsb = (char*)d_ws;
  u16*   ctxPart   = (u16*)wsb;                         // 256*8192 u16  = 4 MB
  float* denomPart = (float*)(wsb + 4194304);           // 256*256 f32   = 256 KB
  u16*   ctxT      = (u16*)(wsb + 4456448);             // 32768 u16     = 64 KB
  float* rdenomF   = (float*)(wsb + 4521984);           // 1024 f32      = 4 KB
  u16*   wbf       = (u16*)(wsb + 4526080);             // 4*65536 u16   = 0.5 MB

  hipLaunchKernelGGL(k_prep, dim3(64), dim3(256), 0, stream,
                     Wk, Wq, Wv, Wr, wbf);
  hipLaunchKernelGGL(k_ctx, dim3(256), dim3(512), 0, stream,
                     x, wbf, bk, bv, ctxPart, denomPart);
  hipLaunchKernelGGL(k_red, dim3(132), dim3(256), 0, stream,
                     ctxPart, denomPart, ctxT, rdenomF);
  hipLaunchKernelGGL(k_out, dim3(256), dim3(512), 0, stream,
                     x, wbf, bq, br, ctxT, rdenomF, out);
}